// Round 11
// baseline (10781.223 us; speedup 1.0000x reference)
//
#include <hip/hip_runtime.h>
#include <hip/hip_bf16.h>

// Problem constants
#define B_   512
#define T_   256
#define F_   256
#define E_   256
#define H_   256
#define G4_  1024      // 4*H
#define K_   768       // H + E + F  (q | r | x)
#define NT   1024      // threads per block (16 waves)
#define NBLK 256       // main kernel blocks (2 molecules each, sequential)

typedef __attribute__((ext_vector_type(8))) short short8;
typedef __attribute__((ext_vector_type(8))) unsigned short ushort8v;
typedef __attribute__((ext_vector_type(4))) unsigned short ushort4v;
typedef __attribute__((ext_vector_type(4))) float f32x4;

__device__ __forceinline__ float bf2f(unsigned int u) {
  union { unsigned int i; float f; } v; v.i = u << 16; return v.f;
}
__device__ __forceinline__ unsigned short f2bf(float f) {
  union { __hip_bfloat16 h; unsigned short u; } v;
  v.h = __float2bfloat16(f); return v.u;
}
__device__ __forceinline__ float sigm(float x) { return 1.f / (1.f + __expf(-x)); }
__device__ __forceinline__ float tanh_fast(float x) { return 1.f - 2.f / (1.f + __expf(2.f * x)); }

// ---------------- setup: pack weights into MFMA B-fragment streams ----------------
// B-frag layout (16x16x32 bf16): lane holds B[n = lane&15][k = (lane>>4)*8 + j]
__global__ void setup_pack(const float* __restrict__ W_ih, const float* __restrict__ W_hh,
                           const float* __restrict__ b_ih, const float* __restrict__ b_hh,
                           const float* __restrict__ W_att, const float* __restrict__ W_embed,
                           unsigned short* __restrict__ Bg, unsigned short* __restrict__ Bx,
                           unsigned short* __restrict__ Ba, unsigned short* __restrict__ We,
                           float* __restrict__ bcomb) {
  int idx = blockIdx.x * blockDim.x + threadIdx.x;
  if (idx < G4_ * K_) {
    int o = idx, j = o & 7, lane = (o >> 3) & 63, rem = o >> 9;
    int kt = rem % 24, ntw = rem / 24;
    int n = ntw * 16 + (lane & 15);
    int k = kt * 32 + ((lane >> 4) << 3) + j;
    float v = W_ih[n * K_ + k] + (k < H_ ? W_hh[n * H_ + k] : 0.f);
    Bg[o] = f2bf(v);
    return;
  }
  idx -= G4_ * K_;
  if (idx < G4_ * F_) {
    int o = idx, j = o & 7, lane = (o >> 3) & 63, rem = o >> 9;
    int kt = rem & 7, ntw = rem >> 3;
    int n = ntw * 16 + (lane & 15);
    int k = kt * 32 + ((lane >> 4) << 3) + j;
    Bx[o] = f2bf(W_ih[n * K_ + 512 + k]);
    return;
  }
  idx -= G4_ * F_;
  if (idx < E_ * H_) {
    int o = idx, j = o & 7, lane = (o >> 3) & 63, rem = o >> 9;
    int kt = rem & 7, ntw = rem >> 3;
    int n = ntw * 16 + (lane & 15), k = kt * 32 + ((lane >> 4) << 3) + j;
    Ba[o] = f2bf(W_att[n * H_ + k]);
    return;
  }
  idx -= E_ * H_;
  if (idx < E_ * F_) {
    int o = idx, j = o & 7, lane = (o >> 3) & 63, rem = o >> 9;
    int kt = rem & 7, ntw = rem >> 3;
    int n = ntw * 16 + (lane & 15), k = kt * 32 + ((lane >> 4) << 3) + j;
    We[o] = f2bf(W_embed[n * F_ + k]);
    return;
  }
  idx -= E_ * F_;
  if (idx < G4_) bcomb[idx] = b_ih[idx] + b_hh[idx];
}

// ---------------- deterministic rank sort of lengths -> perm ----------------
__global__ void sort_kernel(const int* __restrict__ lengths, int* __restrict__ perm) {
  __shared__ int lens[B_];
  int tid = threadIdx.x;
  lens[tid] = lengths[tid];
  __syncthreads();
  int L = lens[tid], pos = 0;
  for (int i = 0; i < B_; ++i) {
    int li = lens[i];
    pos += (li < L) || (li == L && i < tid);
  }
  perm[pos] = tid;
}

// ---------------- gx precompute: gx[b][t][n] = sum_f W_x[n][f] * x[b][t][f] (bf16) ----
__global__ __launch_bounds__(256)
void gx_kernel(const float* __restrict__ features, const unsigned short* __restrict__ Bx,
               unsigned short* __restrict__ gxw) {
  __shared__ unsigned short featL[T_][264];   // 135168 B
  const int b = blockIdx.x;
  const int tid = threadIdx.x, w = tid >> 6, lane = tid & 63;
  const float* fb = features + (size_t)b * T_ * F_;
  for (int c4 = 0; c4 < 64; ++c4) {
    float4 v = *reinterpret_cast<const float4*>(fb + (size_t)tid * F_ + c4 * 4);
    featL[tid][c4 * 4 + 0] = f2bf(v.x);
    featL[tid][c4 * 4 + 1] = f2bf(v.y);
    featL[tid][c4 * 4 + 2] = f2bf(v.z);
    featL[tid][c4 * 4 + 3] = f2bf(v.w);
  }
  __syncthreads();
  const short8* BX = reinterpret_cast<const short8*>(Bx);
  for (int nt = w; nt < 64; nt += 4) {
    short8 Bf[8];
    #pragma unroll
    for (int kt = 0; kt < 8; ++kt) Bf[kt] = BX[(nt * 8 + kt) * 64 + lane];
    for (int mt = 0; mt < 16; ++mt) {
      f32x4 acc = f32x4{0.f, 0.f, 0.f, 0.f};
      #pragma unroll
      for (int kt = 0; kt < 8; ++kt) {
        short8 a = *reinterpret_cast<const short8*>(
            &featL[mt * 16 + (lane & 15)][kt * 32 + ((lane >> 4) << 3)]);
        acc = __builtin_amdgcn_mfma_f32_16x16x32_bf16(a, Bf[kt], acc, 0, 0, 0);
      }
      #pragma unroll
      for (int reg = 0; reg < 4; ++reg) {
        int t = mt * 16 + (lane >> 4) * 4 + reg;
        gxw[((size_t)b * T_ + t) * G4_ + nt * 16 + (lane & 15)] = f2bf(acc[reg]);
      }
    }
  }
}

// ---------------- main: 256 blocks x 16 waves, split-K overlapped schedule ----------
// gates(t+1) = Wq q(t) [P2, overlapped with scores] + Wr r(t) [P5] + gx(t+1).
// __syncthreads drains vmcnt(0), so all stream overlap happens WITHIN a phase.
// No unroll pragma on kt stream loops (R7-R9: forced unroll -> scratch -> 28 GB).
template <int USE_GX>
__global__ __launch_bounds__(NT)
void mol_kernel(const float* __restrict__ features, const int* __restrict__ lengths,
                const int* __restrict__ perm,
                const unsigned short* __restrict__ Bg, const unsigned short* __restrict__ Ba,
                const unsigned short* __restrict__ We, const float* __restrict__ bcomb,
                const float* __restrict__ Wfin, const float* __restrict__ bfin,
                const float* __restrict__ q0, const float* __restrict__ c0,
                const float* __restrict__ r0, const unsigned short* __restrict__ gxw,
                float* __restrict__ out) {
  __shared__ __align__(16) unsigned short emb[T_][264];   // 135168 B
  __shared__ __align__(16) unsigned short qs[784];        // [q|r|x] bf16
  __shared__ __align__(16) unsigned short qpb[272];       // qp bf16
  __shared__ float gates[G4_];
  __shared__ float esc[T_];
  __shared__ float rpart[16][264];                        // 16896 B
  __shared__ float redf[16];

  const int tid  = threadIdx.x;
  const int w    = tid >> 6;          // 0..15
  const int lane = tid & 63;
  const int l15  = lane & 15;
  const float bfinal = bfin[0];
  const int KTL = USE_GX ? 16 : 24;   // total gate K-tiles

  // per-thread constants
  float wfr = 0.f, bc0 = 0.f, bc1 = 0.f, bc2 = 0.f, bc3 = 0.f;
  if (tid < H_) {
    wfr = Wfin[tid];
    bc0 = bcomb[tid]; bc1 = bcomb[H_ + tid];
    bc2 = bcomb[2 * H_ + tid]; bc3 = bcomb[3 * H_ + tid];
  }

  const short8* BW  = reinterpret_cast<const short8*>(Bg);
  const short8* BA  = reinterpret_cast<const short8*>(Ba);
  const short8* WE  = reinterpret_cast<const short8*>(We);
  const short8* qs8 = reinterpret_cast<const short8*>(qs);

  // W_att B-frags resident: wave w owns e-tile w (8 frags = 32 VGPR)
  short8 barf[8];
  #pragma unroll
  for (int kt = 0; kt < 8; ++kt) barf[kt] = BA[(w * 8 + kt) * 64 + lane];

  for (int half = 0; half < 2; ++half) {
    const int b   = perm[half == 0 ? (int)blockIdx.x : (B_ - 1 - (int)blockIdx.x)];
    const int len = lengths[b];
    const float* featb = features + (size_t)b * T_ * F_;
    const unsigned short* gxb = USE_GX ? (gxw + (size_t)b * T_ * G4_) : nullptr;
    const int nmt = (len + 15) >> 4;

    // ---- init state ----
    float cstr = 0.f;
    if (tid < H_) {
      cstr = c0[(size_t)b * H_ + tid];
      qs[tid]       = f2bf(q0[(size_t)b * H_ + tid]);
      qs[H_ + tid]  = f2bf(r0[(size_t)b * E_ + tid]);
      esc[tid] = -3.0e38f;
      qs[512 + tid] = f2bf(featb[tid]);   // x_0 (used by prologue in non-gx)
    }

    // ---- embedding via MFMA into LDS: wave w owns e-tile w ----
    for (int mt = 0; mt < nmt; ++mt) {
      f32x4 ea = f32x4{0.f, 0.f, 0.f, 0.f};
      #pragma unroll
      for (int kt = 0; kt < 8; ++kt) {
        const float* ap_ = featb + (size_t)(mt * 16 + l15) * F_ + kt * 32 + ((lane >> 4) << 3);
        float4 fa = *reinterpret_cast<const float4*>(ap_);
        float4 fb4 = *reinterpret_cast<const float4*>(ap_ + 4);
        short8 a;
        a[0] = (short)f2bf(fa.x);  a[1] = (short)f2bf(fa.y);
        a[2] = (short)f2bf(fa.z);  a[3] = (short)f2bf(fa.w);
        a[4] = (short)f2bf(fb4.x); a[5] = (short)f2bf(fb4.y);
        a[6] = (short)f2bf(fb4.z); a[7] = (short)f2bf(fb4.w);
        ea = __builtin_amdgcn_mfma_f32_16x16x32_bf16(a, WE[(w * 8 + kt) * 64 + lane], ea, 0, 0, 0);
      }
      #pragma unroll
      for (int reg = 0; reg < 4; ++reg) {
        int t = mt * 16 + (lane >> 4) * 4 + reg;
        emb[t][w * 16 + l15] = f2bf(ea[reg]);
      }
    }
    __syncthreads();   // init + emb ready

    // ---- prologue: LSTM(0) from [q0|r0|x0], full-K stream ----
    {
      unsigned short gxu0 = 0, gxu1 = 0, gxu2 = 0, gxu3 = 0;
      if (USE_GX && tid < H_) {
        const unsigned short* gp = gxb + tid;
        gxu0 = gp[0]; gxu1 = gp[256]; gxu2 = gp[512]; gxu3 = gp[768];
      }
      f32x4 acc[4];
      #pragma unroll
      for (int nt = 0; nt < 4; ++nt) acc[nt] = f32x4{0.f, 0.f, 0.f, 0.f};
      short8 cur[4], nxt[4];
      #pragma unroll
      for (int nt = 0; nt < 4; ++nt) cur[nt] = BW[((w * 4 + nt) * 24 + 0) * 64 + lane];
      for (int kt = 0; kt < KTL; ++kt) {     // NO unroll (spill hazard)
        if (kt + 1 < KTL) {
          #pragma unroll
          for (int nt = 0; nt < 4; ++nt) nxt[nt] = BW[((w * 4 + nt) * 24 + kt + 1) * 64 + lane];
        }
        short8 a = qs8[kt * 4 + (lane >> 4)];
        #pragma unroll
        for (int nt = 0; nt < 4; ++nt)
          acc[nt] = __builtin_amdgcn_mfma_f32_16x16x32_bf16(a, cur[nt], acc[nt], 0, 0, 0);
        #pragma unroll
        for (int nt = 0; nt < 4; ++nt) cur[nt] = nxt[nt];
      }
      if (lane < 16) {
        #pragma unroll
        for (int nt = 0; nt < 4; ++nt) gates[w * 64 + nt * 16 + lane] = acc[nt][0];
      }
      __syncthreads();   // gates(0) ready
      if (tid < H_) {
        float ig = gates[tid] + bc0, fg = gates[H_ + tid] + bc1;
        float gg = gates[2 * H_ + tid] + bc2, og = gates[3 * H_ + tid] + bc3;
        if (USE_GX) { ig += bf2f(gxu0); fg += bf2f(gxu1); gg += bf2f(gxu2); og += bf2f(gxu3); }
        float cn = sigm(fg) * cstr + sigm(ig) * tanh_fast(gg);
        float qn = sigm(og) * tanh_fast(cn);
        cstr = cn;
        qs[tid] = f2bf(qn);
        float po = fmaxf(qn, 0.f) * wfr;
        #pragma unroll
        for (int s = 32; s >= 1; s >>= 1) po += __shfl_xor(po, s);
        if (lane == 0) redf[w] = po;
      } else if (lane == 0) {
        redf[w] = 0.f;
      }
    }

    // ---- main loop: iteration i does attn(i) + LSTM(i+1); runs i = 0..len-2 ----
    for (int i = 0; i < len - 1; ++i) {
      __syncthreads();   // B1: q(i), redf(i), [r(i-1) consumed] ready

      // P1: out(i) write + qp = W_att@q(i) + early gx/x loads for step i+1
      if (tid == 0) {
        float s = 0.f;
        #pragma unroll
        for (int k2 = 0; k2 < 16; ++k2) s += redf[k2];
        out[(size_t)b * T_ + i] = s + bfinal;
      }
      unsigned short gxu0 = 0, gxu1 = 0, gxu2 = 0, gxu3 = 0;
      if (USE_GX) {
        if (tid < H_) {
          const unsigned short* gp = gxb + (size_t)(i + 1) * G4_ + tid;
          gxu0 = gp[0]; gxu1 = gp[256]; gxu2 = gp[512]; gxu3 = gp[768];
        }
      } else {
        if (tid < H_) qs[512 + tid] = f2bf(featb[(size_t)(i + 1) * F_ + tid]);  // x(i+1)
      }
      {
        f32x4 aq = f32x4{0.f, 0.f, 0.f, 0.f};
        #pragma unroll
        for (int kt = 0; kt < 8; ++kt) {
          short8 a = qs8[kt * 4 + (lane >> 4)];
          aq = __builtin_amdgcn_mfma_f32_16x16x32_bf16(a, barf[kt], aq, 0, 0, 0);
        }
        if (lane < 16) qpb[w * 16 + lane] = f2bf(aq[0]);
      }
      __syncthreads();   // B2: qpb ready

      // P2 fused: Gq = Wq@q(i) stream (kt 0..7)  ||  scores MFMA (pure LDS)
      f32x4 acc[4];
      {
        #pragma unroll
        for (int nt = 0; nt < 4; ++nt) acc[nt] = f32x4{0.f, 0.f, 0.f, 0.f};
        short8 cur[4], nxt[4];
        #pragma unroll
        for (int nt = 0; nt < 4; ++nt) cur[nt] = BW[((w * 4 + nt) * 24 + 0) * 64 + lane];
        // scores (LDS-only) — executes while Gq loads are in flight
        if (w < nmt) {
          const int mt = w;
          f32x4 sacc = f32x4{0.f, 0.f, 0.f, 0.f};
          #pragma unroll
          for (int kt = 0; kt < 8; ++kt) {
            short8 a  = *reinterpret_cast<const short8*>(
                &emb[mt * 16 + l15][kt * 32 + ((lane >> 4) << 3)]);
            short8 bq = *reinterpret_cast<const short8*>(
                &qpb[kt * 32 + ((lane >> 4) << 3)]);
            sacc = __builtin_amdgcn_mfma_f32_16x16x32_bf16(a, bq, sacc, 0, 0, 0);
          }
          if (l15 == 0) {
            #pragma unroll
            for (int reg = 0; reg < 4; ++reg) {
              int tt = mt * 16 + (lane >> 4) * 4 + reg;
              esc[tt] = (tt < len) ? sacc[reg] : -3.0e38f;
            }
          }
        }
        // Gq stream kt 0..7 (q-range)
        for (int kt = 0; kt < 8; ++kt) {     // NO unroll
          if (kt + 1 < 8) {
            #pragma unroll
            for (int nt = 0; nt < 4; ++nt) nxt[nt] = BW[((w * 4 + nt) * 24 + kt + 1) * 64 + lane];
          }
          short8 a = qs8[kt * 4 + (lane >> 4)];
          #pragma unroll
          for (int nt = 0; nt < 4; ++nt)
            acc[nt] = __builtin_amdgcn_mfma_f32_16x16x32_bf16(a, cur[nt], acc[nt], 0, 0, 0);
          #pragma unroll
          for (int nt = 0; nt < 4; ++nt) cur[nt] = nxt[nt];
        }
      }
      __syncthreads();   // B3: esc ready

      // P3: softmax (per-wave, registers) + rpart partials
      float rinv;
      {
        float v0 = esc[lane], v1 = esc[lane + 64], v2 = esc[lane + 128], v3 = esc[lane + 192];
        float m = fmaxf(fmaxf(v0, v1), fmaxf(v2, v3));
        #pragma unroll
        for (int s = 32; s >= 1; s >>= 1) m = fmaxf(m, __shfl_xor(m, s));
        float p0 = __expf(v0 - m), p1 = __expf(v1 - m), p2 = __expf(v2 - m), p3 = __expf(v3 - m);
        float sv = p0 + p1 + p2 + p3;
        #pragma unroll
        for (int s = 32; s >= 1; s >>= 1) sv += __shfl_xor(sv, s);
        rinv = 1.f / sv;
        const int t0 = w * 16;
        const int tmax = (t0 + 16 < len) ? (t0 + 16) : len;
        const int sbase = (w & 3) * 16;
        const int ksel = w >> 2;
        float vsel = (ksel == 0) ? p0 : (ksel == 1) ? p1 : (ksel == 2) ? p2 : p3;
        float r0a = 0.f, r1a = 0.f, r2a = 0.f, r3a = 0.f;
        for (int k2 = 0; t0 + k2 < tmax; ++k2) {
          float p = __shfl(vsel, sbase + k2);
          ushort4v ev = *reinterpret_cast<const ushort4v*>(&emb[t0 + k2][lane * 4]);
          r0a += p * bf2f(ev[0]); r1a += p * bf2f(ev[1]);
          r2a += p * bf2f(ev[2]); r3a += p * bf2f(ev[3]);
        }
        f32x4 rv = {r0a, r1a, r2a, r3a};
        *reinterpret_cast<f32x4*>(&rpart[w][lane * 4]) = rv;
      }
      __syncthreads();   // B4: rpart ready

      // P4: r(i) = (sum slices) * rinv -> qs[256..511]
      if (tid < H_) {
        float s = 0.f;
        #pragma unroll
        for (int sl = 0; sl < 16; ++sl) s += rpart[sl][tid];
        qs[H_ + tid] = f2bf(s * rinv);
      }
      __syncthreads();   // B5: r ready

      // P5: acc += Wr@r(i) stream (kt 8..KTL-1; includes Wx@x(i+1) in non-gx) -> gates
      {
        short8 cur[4], nxt[4];
        #pragma unroll
        for (int nt = 0; nt < 4; ++nt) cur[nt] = BW[((w * 4 + nt) * 24 + 8) * 64 + lane];
        for (int kt = 8; kt < KTL; ++kt) {     // NO unroll
          if (kt + 1 < KTL) {
            #pragma unroll
            for (int nt = 0; nt < 4; ++nt) nxt[nt] = BW[((w * 4 + nt) * 24 + kt + 1) * 64 + lane];
          }
          short8 a = qs8[kt * 4 + (lane >> 4)];
          #pragma unroll
          for (int nt = 0; nt < 4; ++nt)
            acc[nt] = __builtin_amdgcn_mfma_f32_16x16x32_bf16(a, cur[nt], acc[nt], 0, 0, 0);
          #pragma unroll
          for (int nt = 0; nt < 4; ++nt) cur[nt] = nxt[nt];
        }
        if (lane < 16) {
          #pragma unroll
          for (int nt = 0; nt < 4; ++nt) gates[w * 64 + nt * 16 + lane] = acc[nt][0];
        }
      }
      __syncthreads();   // B6: gates(i+1) ready

      // P6: LSTM(i+1) -> q(i+1), redf
      if (tid < H_) {
        float ig = gates[tid] + bc0, fg = gates[H_ + tid] + bc1;
        float gg = gates[2 * H_ + tid] + bc2, og = gates[3 * H_ + tid] + bc3;
        if (USE_GX) { ig += bf2f(gxu0); fg += bf2f(gxu1); gg += bf2f(gxu2); og += bf2f(gxu3); }
        float cn = sigm(fg) * cstr + sigm(ig) * tanh_fast(gg);
        float qn = sigm(og) * tanh_fast(cn);
        cstr = cn;
        qs[tid] = f2bf(qn);
        float po = fmaxf(qn, 0.f) * wfr;
        #pragma unroll
        for (int s = 32; s >= 1; s >>= 1) po += __shfl_xor(po, s);
        if (lane == 0) redf[w] = po;
      } else if (lane == 0) {
        redf[w] = 0.f;
      }
      // loop-top barrier (B1) fences qs/redf writes
    }

    // epilogue: out(len-1)
    __syncthreads();
    if (tid == 0) {
      float s = 0.f;
      #pragma unroll
      for (int k2 = 0; k2 < 16; ++k2) s += redf[k2];
      out[(size_t)b * T_ + (len - 1)] = s + bfinal;
    }

    // zero padded outputs
    for (int tt = len + tid; tt < T_; tt += NT) out[(size_t)b * T_ + tt] = 0.f;
    __syncthreads();   // emb/qs/esc reuse fence before next molecule
  }
}

extern "C" void kernel_launch(void* const* d_in, const int* in_sizes, int n_in,
                              void* d_out, int out_size, void* d_ws, size_t ws_size,
                              hipStream_t stream) {
  const float* features = (const float*)d_in[0];
  const int*   lengths  = (const int*)d_in[1];
  const float* W_embed  = (const float*)d_in[2];
  const float* W_ih     = (const float*)d_in[3];
  const float* b_ih     = (const float*)d_in[4];
  const float* W_hh     = (const float*)d_in[5];
  const float* b_hh     = (const float*)d_in[6];
  const float* W_att    = (const float*)d_in[7];
  const float* W_final  = (const float*)d_in[8];
  const float* b_final  = (const float*)d_in[9];
  const float* q0       = (const float*)d_in[10];
  const float* c0       = (const float*)d_in[11];
  const float* r0       = (const float*)d_in[12];
  float* out = (float*)d_out;

  char* ws = (char*)d_ws;
  unsigned short* Bg    = (unsigned short*)(ws + 0);          // 1,572,864
  unsigned short* Bx    = (unsigned short*)(ws + 1572864);    //   524,288
  unsigned short* Ba    = (unsigned short*)(ws + 2097152);    //   131,072
  unsigned short* We    = (unsigned short*)(ws + 2228224);    //   131,072
  float*          bcomb = (float*)(ws + 2359296);             //     4,096
  int*            perm  = (int*)(ws + 2363392);               //     2,048
  unsigned short* gxw   = (unsigned short*)(ws + 2365440);    // 268,435,456
  const size_t need_gx = 2365440ull + 268435456ull;
  const int use_gx = (ws_size >= need_gx) ? 1 : 0;

  const int setup_elems = G4_ * K_ + G4_ * F_ + E_ * H_ + E_ * F_ + G4_;  // 1,180,672
  setup_pack<<<(setup_elems + 255) / 256, 256, 0, stream>>>(
      W_ih, W_hh, b_ih, b_hh, W_att, W_embed, Bg, Bx, Ba, We, bcomb);
  sort_kernel<<<1, B_, 0, stream>>>(lengths, perm);
  if (use_gx) {
    gx_kernel<<<B_, 256, 0, stream>>>(features, Bx, gxw);
    mol_kernel<1><<<NBLK, NT, 0, stream>>>(
        features, lengths, perm, Bg, Ba, We, bcomb,
        W_final, b_final, q0, c0, r0, gxw, out);
  } else {
    mol_kernel<0><<<NBLK, NT, 0, stream>>>(
        features, lengths, perm, Bg, Ba, We, bcomb,
        W_final, b_final, q0, c0, r0, gxw, out);
  }
}

// Round 13
// 5332.219 us; speedup vs baseline: 2.0219x; 2.0219x over previous
//
#include <hip/hip_runtime.h>
#include <hip/hip_bf16.h>

// Problem constants
#define B_   512
#define T_   256
#define F_   256
#define E_   256
#define H_   256
#define G4_  1024      // 4*H
#define K_   768       // H + E + F  (q | r | x)
#define NT   512       // threads per block (8 waves) — 128-VGPR budget (R9/R11 lesson)
#define NBLK 256       // main kernel blocks (2 molecules each, sequential)

typedef __attribute__((ext_vector_type(8))) short short8;
typedef __attribute__((ext_vector_type(8))) unsigned short ushort8v;
typedef __attribute__((ext_vector_type(4))) unsigned short ushort4v;
typedef __attribute__((ext_vector_type(4))) float f32x4;

__device__ __forceinline__ float bf2f(unsigned int u) {
  union { unsigned int i; float f; } v; v.i = u << 16; return v.f;
}
__device__ __forceinline__ unsigned short f2bf(float f) {
  union { __hip_bfloat16 h; unsigned short u; } v;
  v.h = __float2bfloat16(f); return v.u;
}
__device__ __forceinline__ float sigm(float x) { return 1.f / (1.f + __expf(-x)); }
__device__ __forceinline__ float tanh_fast(float x) { return 1.f - 2.f / (1.f + __expf(2.f * x)); }

// ---------------- setup: pack weights into MFMA B-fragment streams ----------------
// B-frag layout (16x16x32 bf16): lane holds B[n = lane&15][k = (lane>>4)*8 + j]
__global__ void setup_pack(const float* __restrict__ W_ih, const float* __restrict__ W_hh,
                           const float* __restrict__ b_ih, const float* __restrict__ b_hh,
                           const float* __restrict__ W_att, const float* __restrict__ W_embed,
                           unsigned short* __restrict__ Bg, unsigned short* __restrict__ Bx,
                           unsigned short* __restrict__ Ba, unsigned short* __restrict__ We,
                           float* __restrict__ bcomb) {
  int idx = blockIdx.x * blockDim.x + threadIdx.x;
  if (idx < G4_ * K_) {
    int o = idx, j = o & 7, lane = (o >> 3) & 63, rem = o >> 9;
    int kt = rem % 24, ntw = rem / 24;
    int n = ntw * 16 + (lane & 15);
    int k = kt * 32 + ((lane >> 4) << 3) + j;
    float v = W_ih[n * K_ + k] + (k < H_ ? W_hh[n * H_ + k] : 0.f);
    Bg[o] = f2bf(v);
    return;
  }
  idx -= G4_ * K_;
  if (idx < G4_ * F_) {
    int o = idx, j = o & 7, lane = (o >> 3) & 63, rem = o >> 9;
    int kt = rem & 7, ntw = rem >> 3;
    int n = ntw * 16 + (lane & 15);
    int k = kt * 32 + ((lane >> 4) << 3) + j;
    Bx[o] = f2bf(W_ih[n * K_ + 512 + k]);
    return;
  }
  idx -= G4_ * F_;
  if (idx < E_ * H_) {
    int o = idx, j = o & 7, lane = (o >> 3) & 63, rem = o >> 9;
    int kt = rem & 7, ntw = rem >> 3;
    int n = ntw * 16 + (lane & 15), k = kt * 32 + ((lane >> 4) << 3) + j;
    Ba[o] = f2bf(W_att[n * H_ + k]);
    return;
  }
  idx -= E_ * H_;
  if (idx < E_ * F_) {
    int o = idx, j = o & 7, lane = (o >> 3) & 63, rem = o >> 9;
    int kt = rem & 7, ntw = rem >> 3;
    int n = ntw * 16 + (lane & 15), k = kt * 32 + ((lane >> 4) << 3) + j;
    We[o] = f2bf(W_embed[n * F_ + k]);
    return;
  }
  idx -= E_ * F_;
  if (idx < G4_) bcomb[idx] = b_ih[idx] + b_hh[idx];
}

// ---------------- deterministic rank sort of lengths -> perm ----------------
__global__ void sort_kernel(const int* __restrict__ lengths, int* __restrict__ perm) {
  __shared__ int lens[B_];
  int tid = threadIdx.x;
  lens[tid] = lengths[tid];
  __syncthreads();
  int L = lens[tid], pos = 0;
  for (int i = 0; i < B_; ++i) {
    int li = lens[i];
    pos += (li < L) || (li == L && i < tid);
  }
  perm[pos] = tid;
}

// ---------------- gx precompute: gx[b][t][n] = sum_f W_x[n][f] * x[b][t][f] (bf16) ----
__global__ __launch_bounds__(256)
void gx_kernel(const float* __restrict__ features, const unsigned short* __restrict__ Bx,
               unsigned short* __restrict__ gxw) {
  __shared__ unsigned short featL[T_][264];   // 135168 B
  const int b = blockIdx.x;
  const int tid = threadIdx.x, w = tid >> 6, lane = tid & 63;
  const float* fb = features + (size_t)b * T_ * F_;
  for (int c4 = 0; c4 < 64; ++c4) {
    float4 v = *reinterpret_cast<const float4*>(fb + (size_t)tid * F_ + c4 * 4);
    featL[tid][c4 * 4 + 0] = f2bf(v.x);
    featL[tid][c4 * 4 + 1] = f2bf(v.y);
    featL[tid][c4 * 4 + 2] = f2bf(v.z);
    featL[tid][c4 * 4 + 3] = f2bf(v.w);
  }
  __syncthreads();
  const short8* BX = reinterpret_cast<const short8*>(Bx);
  for (int nt = w; nt < 64; nt += 4) {
    short8 Bf[8];
    #pragma unroll
    for (int kt = 0; kt < 8; ++kt) Bf[kt] = BX[(nt * 8 + kt) * 64 + lane];
    for (int mt = 0; mt < 16; ++mt) {
      f32x4 acc = f32x4{0.f, 0.f, 0.f, 0.f};
      #pragma unroll
      for (int kt = 0; kt < 8; ++kt) {
        short8 a = *reinterpret_cast<const short8*>(
            &featL[mt * 16 + (lane & 15)][kt * 32 + ((lane >> 4) << 3)]);
        acc = __builtin_amdgcn_mfma_f32_16x16x32_bf16(a, Bf[kt], acc, 0, 0, 0);
      }
      #pragma unroll
      for (int reg = 0; reg < 4; ++reg) {
        int t = mt * 16 + (lane >> 4) * 4 + reg;
        gxw[((size_t)b * T_ + t) * G4_ + nt * 16 + (lane & 15)] = f2bf(acc[reg]);
      }
    }
  }
}

// ---------------- main: 256 blocks x 8 waves; split-K schedule, partial in LDS ----
// gates(i+1) = Wq q(i) [P2, after scores issue] + Wr r(i) [P5] (+ gx(i+1)).
// Carried partial Gq lives in gates[] LDS (R11 lesson). Stream loops:
// unroll(disable) (R7-R9 lesson). redf has only 4 valid entries (waves 0-3
// run the LSTM) — R12 bug was summing 8.
template <int USE_GX>
__global__ __launch_bounds__(NT, 2)
void mol_kernel(const float* __restrict__ features, const int* __restrict__ lengths,
                const int* __restrict__ perm,
                const unsigned short* __restrict__ Bg, const unsigned short* __restrict__ Ba,
                const unsigned short* __restrict__ We, const float* __restrict__ bcomb,
                const float* __restrict__ Wfin, const float* __restrict__ bfin,
                const float* __restrict__ q0, const float* __restrict__ c0,
                const float* __restrict__ r0, const unsigned short* __restrict__ gxw,
                float* __restrict__ out) {
  __shared__ __align__(16) unsigned short emb[T_][264];   // 135168 B
  __shared__ __align__(16) unsigned short qs[784];        // [q|r|x] bf16
  __shared__ __align__(16) unsigned short qpb[272];       // qp bf16
  __shared__ float gates[G4_];
  __shared__ float esc[T_];
  __shared__ float rpart[8][264];                         // 8448 B
  __shared__ float redf[8];

  const int tid  = threadIdx.x;
  const int w    = tid >> 6;          // 0..7
  const int lane = tid & 63;
  const int l15  = lane & 15;
  const float bfinal = bfin[0];
  const int KTL = USE_GX ? 16 : 24;

  // per-thread constants
  float wfr = 0.f, bc0 = 0.f, bc1 = 0.f, bc2 = 0.f, bc3 = 0.f;
  if (tid < H_) {
    wfr = Wfin[tid];
    bc0 = bcomb[tid]; bc1 = bcomb[H_ + tid];
    bc2 = bcomb[2 * H_ + tid]; bc3 = bcomb[3 * H_ + tid];
  }

  const short8* BW  = reinterpret_cast<const short8*>(Bg);
  const short8* BA  = reinterpret_cast<const short8*>(Ba);
  const short8* WE  = reinterpret_cast<const short8*>(We);
  const short8* qs8 = reinterpret_cast<const short8*>(qs);

  // W_att B-frags resident (as in the 3.27ms baseline): 64 VGPR
  short8 barf0[8], barf1[8];
  #pragma unroll
  for (int kt = 0; kt < 8; ++kt) {
    barf0[kt] = BA[((2 * w + 0) * 8 + kt) * 64 + lane];
    barf1[kt] = BA[((2 * w + 1) * 8 + kt) * 64 + lane];
  }

  for (int half = 0; half < 2; ++half) {
    const int b   = perm[half == 0 ? (int)blockIdx.x : (B_ - 1 - (int)blockIdx.x)];
    const int len = lengths[b];
    const float* featb = features + (size_t)b * T_ * F_;
    const unsigned short* gxb = USE_GX ? (gxw + (size_t)b * T_ * G4_) : nullptr;
    const int nmt = (len + 15) >> 4;

    // ---- init state ----
    float cstr = 0.f;
    if (tid < H_) {
      cstr = c0[(size_t)b * H_ + tid];
      qs[tid]       = f2bf(q0[(size_t)b * H_ + tid]);
      qs[H_ + tid]  = f2bf(r0[(size_t)b * E_ + tid]);
      esc[tid] = -3.0e38f;
      qs[512 + tid] = f2bf(featb[tid]);   // x_0 (prologue, non-gx path)
    }

    // ---- embedding via MFMA into LDS (wave w owns e-tiles 2w, 2w+1) ----
    for (int mt = 0; mt < nmt; ++mt) {
      f32x4 ea0 = f32x4{0.f, 0.f, 0.f, 0.f};
      f32x4 ea1 = f32x4{0.f, 0.f, 0.f, 0.f};
      #pragma unroll
      for (int kt = 0; kt < 8; ++kt) {
        const float* ap_ = featb + (size_t)(mt * 16 + l15) * F_ + kt * 32 + ((lane >> 4) << 3);
        float4 fa = *reinterpret_cast<const float4*>(ap_);
        float4 fb4 = *reinterpret_cast<const float4*>(ap_ + 4);
        short8 a;
        a[0] = (short)f2bf(fa.x);  a[1] = (short)f2bf(fa.y);
        a[2] = (short)f2bf(fa.z);  a[3] = (short)f2bf(fa.w);
        a[4] = (short)f2bf(fb4.x); a[5] = (short)f2bf(fb4.y);
        a[6] = (short)f2bf(fb4.z); a[7] = (short)f2bf(fb4.w);
        ea0 = __builtin_amdgcn_mfma_f32_16x16x32_bf16(a, WE[((2 * w + 0) * 8 + kt) * 64 + lane], ea0, 0, 0, 0);
        ea1 = __builtin_amdgcn_mfma_f32_16x16x32_bf16(a, WE[((2 * w + 1) * 8 + kt) * 64 + lane], ea1, 0, 0, 0);
      }
      #pragma unroll
      for (int reg = 0; reg < 4; ++reg) {
        int t = mt * 16 + (lane >> 4) * 4 + reg;
        emb[t][(2 * w + 0) * 16 + l15] = f2bf(ea0[reg]);
        emb[t][(2 * w + 1) * 16 + l15] = f2bf(ea1[reg]);
      }
    }
    __syncthreads();   // init + emb ready

    // ---- prologue: gates(0) full-K stream + LSTM(0) ----
    {
      unsigned short gxu0 = 0, gxu1 = 0, gxu2 = 0, gxu3 = 0;
      if (USE_GX && tid < H_) {
        const unsigned short* gp = gxb + tid;
        gxu0 = gp[0]; gxu1 = gp[256]; gxu2 = gp[512]; gxu3 = gp[768];
      }
      f32x4 acc[8];
      #pragma unroll
      for (int nt = 0; nt < 8; ++nt) acc[nt] = f32x4{0.f, 0.f, 0.f, 0.f};
      short8 cur[8], nxt[8];
      #pragma unroll
      for (int nt = 0; nt < 8; ++nt) cur[nt] = BW[((w * 8 + nt) * 24 + 0) * 64 + lane];
      #pragma clang loop unroll(disable)
      for (int kt = 0; kt < KTL; ++kt) {
        if (kt + 1 < KTL) {
          #pragma unroll
          for (int nt = 0; nt < 8; ++nt) nxt[nt] = BW[((w * 8 + nt) * 24 + kt + 1) * 64 + lane];
        }
        short8 a = qs8[kt * 4 + (lane >> 4)];
        #pragma unroll
        for (int nt = 0; nt < 8; ++nt)
          acc[nt] = __builtin_amdgcn_mfma_f32_16x16x32_bf16(a, cur[nt], acc[nt], 0, 0, 0);
        #pragma unroll
        for (int nt = 0; nt < 8; ++nt) cur[nt] = nxt[nt];
      }
      if (lane < 16) {
        #pragma unroll
        for (int nt = 0; nt < 8; ++nt) gates[w * 128 + nt * 16 + lane] = acc[nt][0];
      }
      __syncthreads();   // gates(0) ready
      if (tid < H_) {
        float ig = gates[tid] + bc0, fg = gates[H_ + tid] + bc1;
        float gg = gates[2 * H_ + tid] + bc2, og = gates[3 * H_ + tid] + bc3;
        if (USE_GX) { ig += bf2f(gxu0); fg += bf2f(gxu1); gg += bf2f(gxu2); og += bf2f(gxu3); }
        float cn = sigm(fg) * cstr + sigm(ig) * tanh_fast(gg);
        float qn = sigm(og) * tanh_fast(cn);
        cstr = cn;
        qs[tid] = f2bf(qn);
        float po = fmaxf(qn, 0.f) * wfr;
        #pragma unroll
        for (int s = 32; s >= 1; s >>= 1) po += __shfl_xor(po, s);
        if (lane == 0) redf[w] = po;
      }
    }

    // ---- main loop: iteration i = attn(i) + gates/LSTM(i+1); i = 0..len-2 ----
    for (int i = 0; i < len - 1; ++i) {
      __syncthreads();   // B1: q(i), redf(i) ready; prev gates consumed

      // P1: out(i) + qp = W_att@q(i) (resident frags) + early loads for i+1
      // redf[0..3] only: LSTM runs on waves 0-3 (R12 bug: summed 8 entries)
      if (tid == 0) {
        out[(size_t)b * T_ + i] = redf[0] + redf[1] + redf[2] + redf[3] + bfinal;
      }
      unsigned short gxu0 = 0, gxu1 = 0, gxu2 = 0, gxu3 = 0;
      float xnext = 0.f;
      if (USE_GX) {
        if (tid < H_) {
          const unsigned short* gp = gxb + (size_t)(i + 1) * G4_ + tid;
          gxu0 = gp[0]; gxu1 = gp[256]; gxu2 = gp[512]; gxu3 = gp[768];
        }
      } else {
        if (tid < H_) xnext = featb[(size_t)(i + 1) * F_ + tid];
      }
      {
        f32x4 a0 = f32x4{0.f, 0.f, 0.f, 0.f};
        f32x4 a1 = f32x4{0.f, 0.f, 0.f, 0.f};
        #pragma unroll
        for (int kt = 0; kt < 8; ++kt) {
          short8 a = qs8[kt * 4 + (lane >> 4)];
          a0 = __builtin_amdgcn_mfma_f32_16x16x32_bf16(a, barf0[kt], a0, 0, 0, 0);
          a1 = __builtin_amdgcn_mfma_f32_16x16x32_bf16(a, barf1[kt], a1, 0, 0, 0);
        }
        if (lane < 16) {
          qpb[(2 * w + 0) * 16 + lane] = f2bf(a0[0]);
          qpb[(2 * w + 1) * 16 + lane] = f2bf(a1[0]);
        }
      }
      __syncthreads();   // B2: qpb ready

      // P2: scores MFMA (pure LDS) then Gq = Wq@q(i), kt 0..7 -> gates[] (LDS partial)
      {
        #pragma unroll
        for (int h4 = 0; h4 < 2; ++h4) {
          const int mt = 2 * w + h4;
          if (mt < nmt) {
            f32x4 sacc = f32x4{0.f, 0.f, 0.f, 0.f};
            #pragma unroll
            for (int kt = 0; kt < 8; ++kt) {
              short8 a  = *reinterpret_cast<const short8*>(
                  &emb[mt * 16 + l15][kt * 32 + ((lane >> 4) << 3)]);
              short8 bq = *reinterpret_cast<const short8*>(
                  &qpb[kt * 32 + ((lane >> 4) << 3)]);
              sacc = __builtin_amdgcn_mfma_f32_16x16x32_bf16(a, bq, sacc, 0, 0, 0);
            }
            if (l15 == 0) {
              #pragma unroll
              for (int reg = 0; reg < 4; ++reg) {
                int tt = mt * 16 + (lane >> 4) * 4 + reg;
                esc[tt] = (tt < len) ? sacc[reg] : -3.0e38f;
              }
            }
          }
        }
        f32x4 acc[8];
        #pragma unroll
        for (int nt = 0; nt < 8; ++nt) acc[nt] = f32x4{0.f, 0.f, 0.f, 0.f};
        short8 cur[8], nxt[8];
        #pragma unroll
        for (int nt = 0; nt < 8; ++nt) cur[nt] = BW[((w * 8 + nt) * 24 + 0) * 64 + lane];
        #pragma clang loop unroll(disable)
        for (int kt = 0; kt < 8; ++kt) {
          if (kt + 1 < 8) {
            #pragma unroll
            for (int nt = 0; nt < 8; ++nt) nxt[nt] = BW[((w * 8 + nt) * 24 + kt + 1) * 64 + lane];
          }
          short8 a = qs8[kt * 4 + (lane >> 4)];
          #pragma unroll
          for (int nt = 0; nt < 8; ++nt)
            acc[nt] = __builtin_amdgcn_mfma_f32_16x16x32_bf16(a, cur[nt], acc[nt], 0, 0, 0);
          #pragma unroll
          for (int nt = 0; nt < 8; ++nt) cur[nt] = nxt[nt];
        }
        if (lane < 16) {
          #pragma unroll
          for (int nt = 0; nt < 8; ++nt) gates[w * 128 + nt * 16 + lane] = acc[nt][0];
        }
      }
      __syncthreads();   // B3: esc ready (gates partial also fenced)

      // P3: per-wave register softmax + rpart partials (shuffle p broadcast)
      float rinv;
      {
        float v0 = esc[lane], v1 = esc[lane + 64], v2 = esc[lane + 128], v3 = esc[lane + 192];
        float m = fmaxf(fmaxf(v0, v1), fmaxf(v2, v3));
        #pragma unroll
        for (int s = 32; s >= 1; s >>= 1) m = fmaxf(m, __shfl_xor(m, s));
        float p0 = __expf(v0 - m), p1 = __expf(v1 - m), p2 = __expf(v2 - m), p3 = __expf(v3 - m);
        float sv = p0 + p1 + p2 + p3;
        #pragma unroll
        for (int s = 32; s >= 1; s >>= 1) sv += __shfl_xor(sv, s);
        rinv = 1.f / sv;
        const int t0 = w * 32;
        const int tmax = (t0 + 32 < len) ? (t0 + 32) : len;
        const int sbase = (w & 1) * 32;
        const int ksel = w >> 1;
        float vsel = (ksel == 0) ? p0 : (ksel == 1) ? p1 : (ksel == 2) ? p2 : p3;
        float r0a = 0.f, r1a = 0.f, r2a = 0.f, r3a = 0.f;
        for (int k2 = 0; t0 + k2 < tmax; ++k2) {
          float p = __shfl(vsel, sbase + k2);
          ushort4v ev = *reinterpret_cast<const ushort4v*>(&emb[t0 + k2][lane * 4]);
          r0a += p * bf2f(ev[0]); r1a += p * bf2f(ev[1]);
          r2a += p * bf2f(ev[2]); r3a += p * bf2f(ev[3]);
        }
        f32x4 rv = {r0a, r1a, r2a, r3a};
        *reinterpret_cast<f32x4*>(&rpart[w][lane * 4]) = rv;
      }
      __syncthreads();   // B4: rpart ready

      // P4: r(i) -> qs[256..511]; x(i+1) -> qs[512..] (fallback path)
      if (tid < H_) {
        float s = 0.f;
        #pragma unroll
        for (int sl = 0; sl < 8; ++sl) s += rpart[sl][tid];
        qs[H_ + tid] = f2bf(s * rinv);
        if (!USE_GX) qs[512 + tid] = f2bf(xnext);
      }
      __syncthreads();   // B5: r ready

      // P5: Wr (and Wx in fallback) stream kt 8..KTL-1 -> gates[] += (LDS partial)
      {
        f32x4 acc[8];
        #pragma unroll
        for (int nt = 0; nt < 8; ++nt) acc[nt] = f32x4{0.f, 0.f, 0.f, 0.f};
        short8 cur[8], nxt[8];
        #pragma unroll
        for (int nt = 0; nt < 8; ++nt) cur[nt] = BW[((w * 8 + nt) * 24 + 8) * 64 + lane];
        #pragma clang loop unroll(disable)
        for (int kt = 8; kt < KTL; ++kt) {
          if (kt + 1 < KTL) {
            #pragma unroll
            for (int nt = 0; nt < 8; ++nt) nxt[nt] = BW[((w * 8 + nt) * 24 + kt + 1) * 64 + lane];
          }
          short8 a = qs8[kt * 4 + (lane >> 4)];
          #pragma unroll
          for (int nt = 0; nt < 8; ++nt)
            acc[nt] = __builtin_amdgcn_mfma_f32_16x16x32_bf16(a, cur[nt], acc[nt], 0, 0, 0);
          #pragma unroll
          for (int nt = 0; nt < 8; ++nt) cur[nt] = nxt[nt];
        }
        if (lane < 16) {
          #pragma unroll
          for (int nt = 0; nt < 8; ++nt) {
            int gi = w * 128 + nt * 16 + lane;
            gates[gi] = gates[gi] + acc[nt][0];
          }
        }
      }
      __syncthreads();   // B6: gates(i+1) ready

      // P6: LSTM(i+1) -> q(i+1), redf
      if (tid < H_) {
        float ig = gates[tid] + bc0, fg = gates[H_ + tid] + bc1;
        float gg = gates[2 * H_ + tid] + bc2, og = gates[3 * H_ + tid] + bc3;
        if (USE_GX) { ig += bf2f(gxu0); fg += bf2f(gxu1); gg += bf2f(gxu2); og += bf2f(gxu3); }
        float cn = sigm(fg) * cstr + sigm(ig) * tanh_fast(gg);
        float qn = sigm(og) * tanh_fast(cn);
        cstr = cn;
        qs[tid] = f2bf(qn);
        float po = fmaxf(qn, 0.f) * wfr;
        #pragma unroll
        for (int s = 32; s >= 1; s >>= 1) po += __shfl_xor(po, s);
        if (lane == 0) redf[w] = po;
      }
      // loop-top barrier (B1) fences qs/redf writes
    }

    // epilogue: out(len-1) — redf[0..3] only
    __syncthreads();
    if (tid == 0) {
      out[(size_t)b * T_ + (len - 1)] = redf[0] + redf[1] + redf[2] + redf[3] + bfinal;
    }

    // zero padded outputs
    for (int tt = len + tid; tt < T_; tt += NT) out[(size_t)b * T_ + tt] = 0.f;
    __syncthreads();   // emb/qs/esc reuse fence before next molecule
  }
}

extern "C" void kernel_launch(void* const* d_in, const int* in_sizes, int n_in,
                              void* d_out, int out_size, void* d_ws, size_t ws_size,
                              hipStream_t stream) {
  const float* features = (const float*)d_in[0];
  const int*   lengths  = (const int*)d_in[1];
  const float* W_embed  = (const float*)d_in[2];
  const float* W_ih     = (const float*)d_in[3];
  const float* b_ih     = (const float*)d_in[4];
  const float* W_hh     = (const float*)d_in[5];
  const float* b_hh     = (const float*)d_in[6];
  const float* W_att    = (const float*)d_in[7];
  const float* W_final  = (const float*)d_in[8];
  const float* b_final  = (const float*)d_in[9];
  const float* q0       = (const float*)d_in[10];
  const float* c0       = (const float*)d_in[11];
  const float* r0       = (const float*)d_in[12];
  float* out = (float*)d_out;

  char* ws = (char*)d_ws;
  unsigned short* Bg    = (unsigned short*)(ws + 0);          // 1,572,864
  unsigned short* Bx    = (unsigned short*)(ws + 1572864);    //   524,288
  unsigned short* Ba    = (unsigned short*)(ws + 2097152);    //   131,072
  unsigned short* We    = (unsigned short*)(ws + 2228224);    //   131,072
  float*          bcomb = (float*)(ws + 2359296);             //     4,096
  int*            perm  = (int*)(ws + 2363392);               //     2,048
  unsigned short* gxw   = (unsigned short*)(ws + 2365440);    // 268,435,456
  const size_t need_gx = 2365440ull + 268435456ull;
  const int use_gx = (ws_size >= need_gx) ? 1 : 0;

  const int setup_elems = G4_ * K_ + G4_ * F_ + E_ * H_ + E_ * F_ + G4_;  // 1,180,672
  setup_pack<<<(setup_elems + 255) / 256, 256, 0, stream>>>(
      W_ih, W_hh, b_ih, b_hh, W_att, W_embed, Bg, Bx, Ba, We, bcomb);
  sort_kernel<<<1, B_, 0, stream>>>(lengths, perm);
  if (use_gx) {
    gx_kernel<<<B_, 256, 0, stream>>>(features, Bx, gxw);
    mol_kernel<1><<<NBLK, NT, 0, stream>>>(
        features, lengths, perm, Bg, Ba, We, bcomb,
        W_final, b_final, q0, c0, r0, gxw, out);
  } else {
    mol_kernel<0><<<NBLK, NT, 0, stream>>>(
        features, lengths, perm, Bg, Ba, We, bcomb,
        W_final, b_final, q0, c0, r0, gxw, out);
  }
}

// Round 14
// 3478.976 us; speedup vs baseline: 3.0990x; 1.5327x over previous
//
#include <hip/hip_runtime.h>
#include <hip/hip_bf16.h>

// Problem constants
#define B_   512
#define T_   256
#define F_   256
#define E_   256
#define H_   256
#define G4_  1024      // 4*H
#define K_   768       // H + E + F  (q | r | x)
#define NT   512       // threads per block (8 waves) — 128-VGPR budget
#define NBLK 256       // main kernel blocks (2 molecules each, sequential)

typedef __attribute__((ext_vector_type(8))) short short8;
typedef __attribute__((ext_vector_type(4))) unsigned short ushort4v;
typedef __attribute__((ext_vector_type(4))) float f32x4;

__device__ __forceinline__ float bf2f(unsigned int u) {
  union { unsigned int i; float f; } v; v.i = u << 16; return v.f;
}
__device__ __forceinline__ unsigned short f2bf(float f) {
  union { __hip_bfloat16 h; unsigned short u; } v;
  v.h = __float2bfloat16(f); return v.u;
}
__device__ __forceinline__ float sigm(float x) { return 1.f / (1.f + __expf(-x)); }
__device__ __forceinline__ float tanh_fast(float x) { return 1.f - 2.f / (1.f + __expf(2.f * x)); }

// ---------------- setup: pack weights into MFMA B-fragment streams ----------------
// B-frag layout (16x16x32 bf16): lane holds B[n = lane&15][k = (lane>>4)*8 + j]
__global__ void setup_pack(const float* __restrict__ W_ih, const float* __restrict__ W_hh,
                           const float* __restrict__ b_ih, const float* __restrict__ b_hh,
                           const float* __restrict__ W_att, const float* __restrict__ W_embed,
                           unsigned short* __restrict__ Bg, unsigned short* __restrict__ Bx,
                           unsigned short* __restrict__ Ba, unsigned short* __restrict__ We,
                           float* __restrict__ bcomb) {
  int idx = blockIdx.x * blockDim.x + threadIdx.x;
  if (idx < G4_ * K_) {
    int o = idx, j = o & 7, lane = (o >> 3) & 63, rem = o >> 9;
    int kt = rem % 24, ntw = rem / 24;
    int n = ntw * 16 + (lane & 15);
    int k = kt * 32 + ((lane >> 4) << 3) + j;
    float v = W_ih[n * K_ + k] + (k < H_ ? W_hh[n * H_ + k] : 0.f);
    Bg[o] = f2bf(v);
    return;
  }
  idx -= G4_ * K_;
  if (idx < G4_ * F_) {
    int o = idx, j = o & 7, lane = (o >> 3) & 63, rem = o >> 9;
    int kt = rem & 7, ntw = rem >> 3;
    int n = ntw * 16 + (lane & 15);
    int k = kt * 32 + ((lane >> 4) << 3) + j;
    Bx[o] = f2bf(W_ih[n * K_ + 512 + k]);
    return;
  }
  idx -= G4_ * F_;
  if (idx < E_ * H_) {
    int o = idx, j = o & 7, lane = (o >> 3) & 63, rem = o >> 9;
    int kt = rem & 7, ntw = rem >> 3;
    int n = ntw * 16 + (lane & 15), k = kt * 32 + ((lane >> 4) << 3) + j;
    Ba[o] = f2bf(W_att[n * H_ + k]);
    return;
  }
  idx -= E_ * H_;
  if (idx < E_ * F_) {
    int o = idx, j = o & 7, lane = (o >> 3) & 63, rem = o >> 9;
    int kt = rem & 7, ntw = rem >> 3;
    int n = ntw * 16 + (lane & 15), k = kt * 32 + ((lane >> 4) << 3) + j;
    We[o] = f2bf(W_embed[n * F_ + k]);
    return;
  }
  idx -= E_ * F_;
  if (idx < G4_) bcomb[idx] = b_ih[idx] + b_hh[idx];
}

// ---------------- deterministic rank sort of lengths -> perm ----------------
__global__ void sort_kernel(const int* __restrict__ lengths, int* __restrict__ perm) {
  __shared__ int lens[B_];
  int tid = threadIdx.x;
  lens[tid] = lengths[tid];
  __syncthreads();
  int L = lens[tid], pos = 0;
  for (int i = 0; i < B_; ++i) {
    int li = lens[i];
    pos += (li < L) || (li == L && i < tid);
  }
  perm[pos] = tid;
}

// ---------------- gx precompute: gx[b][t][n] = sum_f W_x[n][f] * x[b][t][f] (bf16) ----
__global__ __launch_bounds__(256)
void gx_kernel(const float* __restrict__ features, const unsigned short* __restrict__ Bx,
               unsigned short* __restrict__ gxw) {
  __shared__ unsigned short featL[T_][264];   // 135168 B
  const int b = blockIdx.x;
  const int tid = threadIdx.x, w = tid >> 6, lane = tid & 63;
  const float* fb = features + (size_t)b * T_ * F_;
  for (int c4 = 0; c4 < 64; ++c4) {
    float4 v = *reinterpret_cast<const float4*>(fb + (size_t)tid * F_ + c4 * 4);
    featL[tid][c4 * 4 + 0] = f2bf(v.x);
    featL[tid][c4 * 4 + 1] = f2bf(v.y);
    featL[tid][c4 * 4 + 2] = f2bf(v.z);
    featL[tid][c4 * 4 + 3] = f2bf(v.w);
  }
  __syncthreads();
  const short8* BX = reinterpret_cast<const short8*>(Bx);
  for (int nt = w; nt < 64; nt += 4) {
    short8 Bf[8];
    #pragma unroll
    for (int kt = 0; kt < 8; ++kt) Bf[kt] = BX[(nt * 8 + kt) * 64 + lane];
    for (int mt = 0; mt < 16; ++mt) {
      f32x4 acc = f32x4{0.f, 0.f, 0.f, 0.f};
      #pragma unroll
      for (int kt = 0; kt < 8; ++kt) {
        short8 a = *reinterpret_cast<const short8*>(
            &featL[mt * 16 + (lane & 15)][kt * 32 + ((lane >> 4) << 3)]);
        acc = __builtin_amdgcn_mfma_f32_16x16x32_bf16(a, Bf[kt], acc, 0, 0, 0);
      }
      #pragma unroll
      for (int reg = 0; reg < 4; ++reg) {
        int t = mt * 16 + (lane >> 4) * 4 + reg;
        gxw[((size_t)b * T_ + t) * G4_ + nt * 16 + (lane & 15)] = f2bf(acc[reg]);
      }
    }
  }
}

// ---------------- main: 256 blocks x 8 waves; split-K, reg-disciplined ----------
// gates(i+1) = Wq q(i) [P3, fused with softmax+rpart] + Wr r(i) [P5] (+ gx(i+1)).
// All stream loops: TWO nt-passes of 4 (peak ~60 VGPR/phase), partials in gates[]
// LDS. Nothing register-carried across barriers except 4 u16 gx values (R6-proven).
template <int USE_GX>
__global__ __launch_bounds__(NT, 2)
void mol_kernel(const float* __restrict__ features, const int* __restrict__ lengths,
                const int* __restrict__ perm,
                const unsigned short* __restrict__ Bg, const unsigned short* __restrict__ Ba,
                const unsigned short* __restrict__ We, const float* __restrict__ bcomb,
                const float* __restrict__ Wfin, const float* __restrict__ bfin,
                const float* __restrict__ q0, const float* __restrict__ c0,
                const float* __restrict__ r0, const unsigned short* __restrict__ gxw,
                float* __restrict__ out) {
  __shared__ __align__(16) unsigned short emb[T_][264];   // 135168 B
  __shared__ __align__(16) unsigned short qs[784];        // [q|r|x] bf16
  __shared__ __align__(16) unsigned short qpb[272];       // qp bf16
  __shared__ float gates[G4_];
  __shared__ float esc[T_];
  __shared__ float rpart[8][264];                         // 8448 B
  __shared__ float redf[8];

  const int tid  = threadIdx.x;
  const int w    = tid >> 6;          // 0..7
  const int lane = tid & 63;
  const int l15  = lane & 15;
  const float bfinal = bfin[0];
  const int KTL = USE_GX ? 16 : 24;

  float wfr = 0.f, bc0 = 0.f, bc1 = 0.f, bc2 = 0.f, bc3 = 0.f;
  if (tid < H_) {
    wfr = Wfin[tid];
    bc0 = bcomb[tid]; bc1 = bcomb[H_ + tid];
    bc2 = bcomb[2 * H_ + tid]; bc3 = bcomb[3 * H_ + tid];
  }

  const short8* BW  = reinterpret_cast<const short8*>(Bg);
  const short8* BA  = reinterpret_cast<const short8*>(Ba);
  const short8* WE  = reinterpret_cast<const short8*>(We);
  const short8* qs8 = reinterpret_cast<const short8*>(qs);

  for (int half = 0; half < 2; ++half) {
    const int b   = perm[half == 0 ? (int)blockIdx.x : (B_ - 1 - (int)blockIdx.x)];
    const int len = lengths[b];
    const float* featb = features + (size_t)b * T_ * F_;
    const unsigned short* gxb = USE_GX ? (gxw + (size_t)b * T_ * G4_) : nullptr;
    const int nmt = (len + 15) >> 4;

    // ---- init state ----
    float cstr = 0.f;
    if (tid < H_) {
      cstr = c0[(size_t)b * H_ + tid];
      qs[tid]       = f2bf(q0[(size_t)b * H_ + tid]);
      qs[H_ + tid]  = f2bf(r0[(size_t)b * E_ + tid]);
      esc[tid] = -3.0e38f;
      qs[512 + tid] = f2bf(featb[tid]);   // x_0
    }

    // ---- embedding via MFMA into LDS (wave w owns e-tiles 2w, 2w+1) ----
    for (int mt = 0; mt < nmt; ++mt) {
      f32x4 ea0 = f32x4{0.f, 0.f, 0.f, 0.f};
      f32x4 ea1 = f32x4{0.f, 0.f, 0.f, 0.f};
      #pragma unroll
      for (int kt = 0; kt < 8; ++kt) {
        const float* ap_ = featb + (size_t)(mt * 16 + l15) * F_ + kt * 32 + ((lane >> 4) << 3);
        float4 fa = *reinterpret_cast<const float4*>(ap_);
        float4 fb4 = *reinterpret_cast<const float4*>(ap_ + 4);
        short8 a;
        a[0] = (short)f2bf(fa.x);  a[1] = (short)f2bf(fa.y);
        a[2] = (short)f2bf(fa.z);  a[3] = (short)f2bf(fa.w);
        a[4] = (short)f2bf(fb4.x); a[5] = (short)f2bf(fb4.y);
        a[6] = (short)f2bf(fb4.z); a[7] = (short)f2bf(fb4.w);
        ea0 = __builtin_amdgcn_mfma_f32_16x16x32_bf16(a, WE[((2 * w + 0) * 8 + kt) * 64 + lane], ea0, 0, 0, 0);
        ea1 = __builtin_amdgcn_mfma_f32_16x16x32_bf16(a, WE[((2 * w + 1) * 8 + kt) * 64 + lane], ea1, 0, 0, 0);
      }
      #pragma unroll
      for (int reg = 0; reg < 4; ++reg) {
        int t = mt * 16 + (lane >> 4) * 4 + reg;
        emb[t][(2 * w + 0) * 16 + l15] = f2bf(ea0[reg]);
        emb[t][(2 * w + 1) * 16 + l15] = f2bf(ea1[reg]);
      }
    }
    __syncthreads();   // init + emb ready

    // ---- prologue: gates(0) full-K stream (two nt-passes of 4) + LSTM(0) ----
    {
      unsigned short gxu0 = 0, gxu1 = 0, gxu2 = 0, gxu3 = 0;
      if (USE_GX && tid < H_) {
        const unsigned short* gp = gxb + tid;
        gxu0 = gp[0]; gxu1 = gp[256]; gxu2 = gp[512]; gxu3 = gp[768];
      }
      #pragma unroll
      for (int pass = 0; pass < 2; ++pass) {
        const int ntb = pass * 4;
        f32x4 acc[4];
        #pragma unroll
        for (int nt = 0; nt < 4; ++nt) acc[nt] = f32x4{0.f, 0.f, 0.f, 0.f};
        short8 cur[4], nxt[4];
        #pragma unroll
        for (int nt = 0; nt < 4; ++nt) cur[nt] = BW[((w * 8 + ntb + nt) * 24 + 0) * 64 + lane];
        #pragma clang loop unroll(disable)
        for (int kt = 0; kt < KTL; ++kt) {
          if (kt + 1 < KTL) {
            #pragma unroll
            for (int nt = 0; nt < 4; ++nt) nxt[nt] = BW[((w * 8 + ntb + nt) * 24 + kt + 1) * 64 + lane];
          }
          short8 a = qs8[kt * 4 + (lane >> 4)];
          #pragma unroll
          for (int nt = 0; nt < 4; ++nt)
            acc[nt] = __builtin_amdgcn_mfma_f32_16x16x32_bf16(a, cur[nt], acc[nt], 0, 0, 0);
          #pragma unroll
          for (int nt = 0; nt < 4; ++nt) cur[nt] = nxt[nt];
        }
        if (lane < 16) {
          #pragma unroll
          for (int nt = 0; nt < 4; ++nt) gates[w * 128 + (ntb + nt) * 16 + lane] = acc[nt][0];
        }
      }
      __syncthreads();   // gates(0) ready
      if (tid < H_) {
        float ig = gates[tid] + bc0, fg = gates[H_ + tid] + bc1;
        float gg = gates[2 * H_ + tid] + bc2, og = gates[3 * H_ + tid] + bc3;
        if (USE_GX) { ig += bf2f(gxu0); fg += bf2f(gxu1); gg += bf2f(gxu2); og += bf2f(gxu3); }
        float cn = sigm(fg) * cstr + sigm(ig) * tanh_fast(gg);
        float qn = sigm(og) * tanh_fast(cn);
        cstr = cn;
        qs[tid] = f2bf(qn);
        float po = fmaxf(qn, 0.f) * wfr;
        #pragma unroll
        for (int s = 32; s >= 1; s >>= 1) po += __shfl_xor(po, s);
        if (lane == 0) redf[w] = po;
      }
    }

    // ---- main loop: iteration i = attn(i) + gates/LSTM(i+1); i = 0..len-2 ----
    for (int i = 0; i < len - 1; ++i) {
      __syncthreads();   // B1: q(i), redf(i) ready

      // P1: out(i) [redf 0..3] + qp = W_att@q(i), Ba streamed (2 frags/wave, prefetch)
      if (tid == 0) {
        out[(size_t)b * T_ + i] = redf[0] + redf[1] + redf[2] + redf[3] + bfinal;
      }
      unsigned short gxu0 = 0, gxu1 = 0, gxu2 = 0, gxu3 = 0;
      float xnext = 0.f;
      if (USE_GX) {
        if (tid < H_) {
          const unsigned short* gp = gxb + (size_t)(i + 1) * G4_ + tid;
          gxu0 = gp[0]; gxu1 = gp[256]; gxu2 = gp[512]; gxu3 = gp[768];
        }
      } else {
        if (tid < H_) xnext = featb[(size_t)(i + 1) * F_ + tid];
      }
      {
        f32x4 a0 = f32x4{0.f, 0.f, 0.f, 0.f};
        f32x4 a1 = f32x4{0.f, 0.f, 0.f, 0.f};
        short8 c0f = BA[((2 * w + 0) * 8 + 0) * 64 + lane];
        short8 c1f = BA[((2 * w + 1) * 8 + 0) * 64 + lane];
        short8 n0f, n1f;
        #pragma clang loop unroll(disable)
        for (int kt = 0; kt < 8; ++kt) {
          if (kt + 1 < 8) {
            n0f = BA[((2 * w + 0) * 8 + kt + 1) * 64 + lane];
            n1f = BA[((2 * w + 1) * 8 + kt + 1) * 64 + lane];
          }
          short8 a = qs8[kt * 4 + (lane >> 4)];
          a0 = __builtin_amdgcn_mfma_f32_16x16x32_bf16(a, c0f, a0, 0, 0, 0);
          a1 = __builtin_amdgcn_mfma_f32_16x16x32_bf16(a, c1f, a1, 0, 0, 0);
          c0f = n0f; c1f = n1f;
        }
        if (lane < 16) {
          qpb[(2 * w + 0) * 16 + lane] = f2bf(a0[0]);
          qpb[(2 * w + 1) * 16 + lane] = f2bf(a1[0]);
        }
      }
      __syncthreads();   // B2: qpb ready

      // P2: scores via MFMA (pure LDS)
      {
        #pragma unroll
        for (int h4 = 0; h4 < 2; ++h4) {
          const int mt = 2 * w + h4;
          if (mt < nmt) {
            f32x4 sacc = f32x4{0.f, 0.f, 0.f, 0.f};
            #pragma unroll
            for (int kt = 0; kt < 8; ++kt) {
              short8 a  = *reinterpret_cast<const short8*>(
                  &emb[mt * 16 + l15][kt * 32 + ((lane >> 4) << 3)]);
              short8 bq = *reinterpret_cast<const short8*>(
                  &qpb[kt * 32 + ((lane >> 4) << 3)]);
              sacc = __builtin_amdgcn_mfma_f32_16x16x32_bf16(a, bq, sacc, 0, 0, 0);
            }
            if (l15 == 0) {
              #pragma unroll
              for (int reg = 0; reg < 4; ++reg) {
                int tt = mt * 16 + (lane >> 4) * 4 + reg;
                esc[tt] = (tt < len) ? sacc[reg] : -3.0e38f;
              }
            }
          }
        }
      }
      __syncthreads();   // B3: esc ready

      // P3: softmax (reg) + [pass0: Wq stream nt0-3 FUSED with rpart] + [pass1: Wq nt4-7]
      float rinv;
      {
        float v0 = esc[lane], v1 = esc[lane + 64], v2 = esc[lane + 128], v3 = esc[lane + 192];
        float m = fmaxf(fmaxf(v0, v1), fmaxf(v2, v3));
        #pragma unroll
        for (int s = 32; s >= 1; s >>= 1) m = fmaxf(m, __shfl_xor(m, s));
        float p0 = __expf(v0 - m), p1 = __expf(v1 - m), p2 = __expf(v2 - m), p3 = __expf(v3 - m);
        float sv = p0 + p1 + p2 + p3;
        #pragma unroll
        for (int s = 32; s >= 1; s >>= 1) sv += __shfl_xor(sv, s);
        rinv = 1.f / sv;
        const int t0 = w * 32;
        const int tmax = (t0 + 32 < len) ? (t0 + 32) : len;
        const int sbase = (w & 1) * 32;
        const int ksel = w >> 1;
        float vsel = (ksel == 0) ? p0 : (ksel == 1) ? p1 : (ksel == 2) ? p2 : p3;
        // pass 0: Wq nt 0..3 over kt 0..7, 4 rpart rows folded into each kt
        {
          f32x4 acc[4];
          #pragma unroll
          for (int nt = 0; nt < 4; ++nt) acc[nt] = f32x4{0.f, 0.f, 0.f, 0.f};
          short8 cur[4], nxt[4];
          #pragma unroll
          for (int nt = 0; nt < 4; ++nt) cur[nt] = BW[((w * 8 + nt) * 24 + 0) * 64 + lane];
          float r0a = 0.f, r1a = 0.f, r2a = 0.f, r3a = 0.f;
          #pragma clang loop unroll(disable)
          for (int kt = 0; kt < 8; ++kt) {
            if (kt + 1 < 8) {
              #pragma unroll
              for (int nt = 0; nt < 4; ++nt) nxt[nt] = BW[((w * 8 + nt) * 24 + kt + 1) * 64 + lane];
            }
            short8 a = qs8[kt * 4 + (lane >> 4)];
            #pragma unroll
            for (int nt = 0; nt < 4; ++nt)
              acc[nt] = __builtin_amdgcn_mfma_f32_16x16x32_bf16(a, cur[nt], acc[nt], 0, 0, 0);
            #pragma unroll
            for (int jj = 0; jj < 4; ++jj) {
              int row = t0 + kt * 4 + jj;
              if (row < tmax) {
                float p = __shfl(vsel, sbase + kt * 4 + jj);
                ushort4v ev = *reinterpret_cast<const ushort4v*>(&emb[row][lane * 4]);
                r0a += p * bf2f(ev[0]); r1a += p * bf2f(ev[1]);
                r2a += p * bf2f(ev[2]); r3a += p * bf2f(ev[3]);
              }
            }
            #pragma unroll
            for (int nt = 0; nt < 4; ++nt) cur[nt] = nxt[nt];
          }
          f32x4 rv = {r0a, r1a, r2a, r3a};
          *reinterpret_cast<f32x4*>(&rpart[w][lane * 4]) = rv;
          if (lane < 16) {
            #pragma unroll
            for (int nt = 0; nt < 4; ++nt) gates[w * 128 + nt * 16 + lane] = acc[nt][0];
          }
        }
        // pass 1: Wq nt 4..7 over kt 0..7 (plain)
        {
          f32x4 acc[4];
          #pragma unroll
          for (int nt = 0; nt < 4; ++nt) acc[nt] = f32x4{0.f, 0.f, 0.f, 0.f};
          short8 cur[4], nxt[4];
          #pragma unroll
          for (int nt = 0; nt < 4; ++nt) cur[nt] = BW[((w * 8 + 4 + nt) * 24 + 0) * 64 + lane];
          #pragma clang loop unroll(disable)
          for (int kt = 0; kt < 8; ++kt) {
            if (kt + 1 < 8) {
              #pragma unroll
              for (int nt = 0; nt < 4; ++nt) nxt[nt] = BW[((w * 8 + 4 + nt) * 24 + kt + 1) * 64 + lane];
            }
            short8 a = qs8[kt * 4 + (lane >> 4)];
            #pragma unroll
            for (int nt = 0; nt < 4; ++nt)
              acc[nt] = __builtin_amdgcn_mfma_f32_16x16x32_bf16(a, cur[nt], acc[nt], 0, 0, 0);
            #pragma unroll
            for (int nt = 0; nt < 4; ++nt) cur[nt] = nxt[nt];
          }
          if (lane < 16) {
            #pragma unroll
            for (int nt = 0; nt < 4; ++nt) gates[w * 128 + (4 + nt) * 16 + lane] = acc[nt][0];
          }
        }
      }
      __syncthreads();   // B4: rpart + Wq partial ready

      // P4: r(i) -> qs[256..511]; x(i+1) -> qs[512..] (fallback)
      if (tid < H_) {
        float s = 0.f;
        #pragma unroll
        for (int sl = 0; sl < 8; ++sl) s += rpart[sl][tid];
        qs[H_ + tid] = f2bf(s * rinv);
        if (!USE_GX) qs[512 + tid] = f2bf(xnext);
      }
      __syncthreads();   // B5: r ready

      // P5: Wr (and Wx fallback) stream kt 8..KTL-1, two nt-passes -> gates[] +=
      #pragma unroll
      for (int pass = 0; pass < 2; ++pass) {
        const int ntb = pass * 4;
        f32x4 acc[4];
        #pragma unroll
        for (int nt = 0; nt < 4; ++nt) acc[nt] = f32x4{0.f, 0.f, 0.f, 0.f};
        short8 cur[4], nxt[4];
        #pragma unroll
        for (int nt = 0; nt < 4; ++nt) cur[nt] = BW[((w * 8 + ntb + nt) * 24 + 8) * 64 + lane];
        #pragma clang loop unroll(disable)
        for (int kt = 8; kt < KTL; ++kt) {
          if (kt + 1 < KTL) {
            #pragma unroll
            for (int nt = 0; nt < 4; ++nt) nxt[nt] = BW[((w * 8 + ntb + nt) * 24 + kt + 1) * 64 + lane];
          }
          short8 a = qs8[kt * 4 + (lane >> 4)];
          #pragma unroll
          for (int nt = 0; nt < 4; ++nt)
            acc[nt] = __builtin_amdgcn_mfma_f32_16x16x32_bf16(a, cur[nt], acc[nt], 0, 0, 0);
          #pragma unroll
          for (int nt = 0; nt < 4; ++nt) cur[nt] = nxt[nt];
        }
        if (lane < 16) {
          #pragma unroll
          for (int nt = 0; nt < 4; ++nt) {
            int gi = w * 128 + (ntb + nt) * 16 + lane;
            gates[gi] = gates[gi] + acc[nt][0];
          }
        }
      }
      __syncthreads();   // B6: gates(i+1) ready

      // P6: LSTM(i+1) -> q(i+1), redf
      if (tid < H_) {
        float ig = gates[tid] + bc0, fg = gates[H_ + tid] + bc1;
        float gg = gates[2 * H_ + tid] + bc2, og = gates[3 * H_ + tid] + bc3;
        if (USE_GX) { ig += bf2f(gxu0); fg += bf2f(gxu1); gg += bf2f(gxu2); og += bf2f(gxu3); }
        float cn = sigm(fg) * cstr + sigm(ig) * tanh_fast(gg);
        float qn = sigm(og) * tanh_fast(cn);
        cstr = cn;
        qs[tid] = f2bf(qn);
        float po = fmaxf(qn, 0.f) * wfr;
        #pragma unroll
        for (int s = 32; s >= 1; s >>= 1) po += __shfl_xor(po, s);
        if (lane == 0) redf[w] = po;
      }
      // loop-top barrier (B1) fences qs/redf writes
    }

    // epilogue: out(len-1) — redf[0..3]
    __syncthreads();
    if (tid == 0) {
      out[(size_t)b * T_ + (len - 1)] = redf[0] + redf[1] + redf[2] + redf[3] + bfinal;
    }

    // zero padded outputs
    for (int tt = len + tid; tt < T_; tt += NT) out[(size_t)b * T_ + tt] = 0.f;
    __syncthreads();   // emb/qs/esc reuse fence before next molecule
  }
}

extern "C" void kernel_launch(void* const* d_in, const int* in_sizes, int n_in,
                              void* d_out, int out_size, void* d_ws, size_t ws_size,
                              hipStream_t stream) {
  const float* features = (const float*)d_in[0];
  const int*   lengths  = (const int*)d_in[1];
  const float* W_embed  = (const float*)d_in[2];
  const float* W_ih     = (const float*)d_in[3];
  const float* b_ih     = (const float*)d_in[4];
  const float* W_hh     = (const float*)d_in[5];
  const float* b_hh     = (const float*)d_in[6];
  const float* W_att    = (const float*)d_in[7];
  const float* W_final  = (const float*)d_in[8];
  const float* b_final  = (const float*)d_in[9];
  const float* q0       = (const float*)d_in[10];
  const float* c0       = (const float*)d_in[11];
  const float* r0       = (const float*)d_in[12];
  float* out = (float*)d_out;

  char* ws = (char*)d_ws;
  unsigned short* Bg    = (unsigned short*)(ws + 0);          // 1,572,864
  unsigned short* Bx    = (unsigned short*)(ws + 1572864);    //   524,288
  unsigned short* Ba    = (unsigned short*)(ws + 2097152);    //   131,072
  unsigned short* We    = (unsigned short*)(ws + 2228224);    //   131,072
  float*          bcomb = (float*)(ws + 2359296);             //     4,096
  int*            perm  = (int*)(ws + 2363392);               //     2,048
  unsigned short* gxw   = (unsigned short*)(ws + 2365440);    // 268,435,456
  const size_t need_gx = 2365440ull + 268435456ull;
  const int use_gx = (ws_size >= need_gx) ? 1 : 0;

  const int setup_elems = G4_ * K_ + G4_ * F_ + E_ * H_ + E_ * F_ + G4_;  // 1,180,672
  setup_pack<<<(setup_elems + 255) / 256, 256, 0, stream>>>(
      W_ih, W_hh, b_ih, b_hh, W_att, W_embed, Bg, Bx, Ba, We, bcomb);
  sort_kernel<<<1, B_, 0, stream>>>(lengths, perm);
  if (use_gx) {
    gx_kernel<<<B_, 256, 0, stream>>>(features, Bx, gxw);
    mol_kernel<1><<<NBLK, NT, 0, stream>>>(
        features, lengths, perm, Bg, Ba, We, bcomb,
        W_final, b_final, q0, c0, r0, gxw, out);
  } else {
    mol_kernel<0><<<NBLK, NT, 0, stream>>>(
        features, lengths, perm, Bg, Ba, We, bcomb,
        W_final, b_final, q0, c0, r0, gxw, out);
  }
}